// Round 5
// baseline (344.308 us; speedup 1.0000x reference)
//
#include <hip/hip_runtime.h>

#define Hh 240
#define Ww 304
#define IN_CH 16
#define OUT_CH 32
#define Bb 8
#define N_PER 65536
#define N_EV (Bb * N_PER)      // 524288
#define CIN (IN_CH + 2)        // 18
#define NSEG (Bb * Hh * Ww)    // 583680 = 570 * 1024 = 2280 * 256
#define NBLK 570               // scan blocks of 1024 elems

__device__ __forceinline__ unsigned short f2bf(float x) {
  unsigned u = __float_as_uint(x);
  unsigned r = u + 0x7fffu + ((u >> 16) & 1u);  // RNE
  return (unsigned short)(r >> 16);
}
__device__ __forceinline__ float bf2f(unsigned short b) {
  return __uint_as_float(((unsigned)b) << 16);
}

// ---- A: histogram + rank per event (one atomic pass) -----------------------
__global__ __launch_bounds__(256) void hist_rank_kernel(
    const float* __restrict__ events, const int* __restrict__ offsets,
    int* __restrict__ hist, int* __restrict__ keyArr, int* __restrict__ rankArr) {
  int i = blockIdx.x * blockDim.x + threadIdx.x;
  float4 ev = ((const float4*)events)[i];
  int yi = (int)rintf(ev.y * (float)Hh);
  yi = min(max(yi, 0), Hh - 1);
  int xi = (int)rintf(ev.x * (float)Ww);
  xi = min(max(xi, 0), Ww - 1);
  int b = 0;
#pragma unroll
  for (int j = 0; j < Bb; j++) b += (offsets[j] <= i) ? 1 : 0;
  int key = (b * Hh + yi) * Ww + xi;
  int pol = (ev.w != 0.0f) ? 1 : 0;
  keyArr[i] = key | (pol << 31);
  rankArr[i] = atomicAdd(&hist[key], 1);
}

// ---- S1: per-1024-block exclusive scan + block totals ----------------------
__global__ __launch_bounds__(256) void scan1_kernel(
    const int* __restrict__ hist, int* __restrict__ baseLocal,
    int* __restrict__ blockSum) {
  __shared__ int lds[256];
  int b = blockIdx.x, t = threadIdx.x;
  int idx = b * 1024 + t * 4;
  int4 v = *(const int4*)(hist + idx);
  int s0 = v.x, s1 = s0 + v.y, s2 = s1 + v.z, s3 = s2 + v.w;
  lds[t] = s3;
  __syncthreads();
  int val = s3;
  for (int off = 1; off < 256; off <<= 1) {
    int n = (t >= off) ? lds[t - off] : 0;
    __syncthreads();
    val += n;
    lds[t] = val;
    __syncthreads();
  }
  int excl = val - s3;
  int4 o;
  o.x = excl; o.y = excl + s0; o.z = excl + s1; o.w = excl + s2;
  *(int4*)(baseLocal + idx) = o;
  if (t == 255) blockSum[b] = val;
}

// ---- S2: scan of 570 block totals -----------------------------------------
__global__ __launch_bounds__(1024) void scan2_kernel(
    const int* __restrict__ blockSum, int* __restrict__ blockOffset) {
  __shared__ int lds[1024];
  int t = threadIdx.x;
  int v = (t < NBLK) ? blockSum[t] : 0;
  lds[t] = v;
  __syncthreads();
  int val = v;
  for (int off = 1; off < 1024; off <<= 1) {
    int n = (t >= off) ? lds[t - off] : 0;
    __syncthreads();
    val += n;
    lds[t] = val;
    __syncthreads();
  }
  if (t < NBLK) blockOffset[t] = val - v;
  if (t == 0) blockOffset[NBLK] = lds[1023];  // = N_EV
}

// ---- B: scatter features (bf16) + meta into sorted order -------------------
__global__ __launch_bounds__(256) void scatter_feat_kernel(
    const float* __restrict__ features, const int* __restrict__ keyArr,
    const int* __restrict__ rankArr, const int* __restrict__ baseLocal,
    const int* __restrict__ blockOffset, uint4* __restrict__ sortedFeat,
    int* __restrict__ sortedMeta) {
  int i = blockIdx.x * blockDim.x + threadIdx.x;
  int meta = keyArr[i];
  int key = meta & 0x7fffffff;
  int pos = baseLocal[key] + blockOffset[key >> 10] + rankArr[i];
  const float4* f = (const float4*)(features + (size_t)i * IN_CH);
  float4 f0 = f[0], f1 = f[1], f2 = f[2], f3 = f[3];
  uint4 w0, w1;
  w0.x = (unsigned)f2bf(f0.x) | ((unsigned)f2bf(f0.y) << 16);
  w0.y = (unsigned)f2bf(f0.z) | ((unsigned)f2bf(f0.w) << 16);
  w0.z = (unsigned)f2bf(f1.x) | ((unsigned)f2bf(f1.y) << 16);
  w0.w = (unsigned)f2bf(f1.z) | ((unsigned)f2bf(f1.w) << 16);
  w1.x = (unsigned)f2bf(f2.x) | ((unsigned)f2bf(f2.y) << 16);
  w1.y = (unsigned)f2bf(f2.z) | ((unsigned)f2bf(f2.w) << 16);
  w1.z = (unsigned)f2bf(f3.x) | ((unsigned)f2bf(f3.y) << 16);
  w1.w = (unsigned)f2bf(f3.z) | ((unsigned)f2bf(f3.w) << 16);
  sortedFeat[(size_t)pos * 2] = w0;
  sortedFeat[(size_t)pos * 2 + 1] = w1;
  sortedMeta[pos] = i | (meta & 0x80000000);
}

// ---- C: per-pixel streaming accumulate + normalize + compact ---------------
// dense is SoA: dense[c * NSEG + p]. Worklist push is wave-aggregated.
__global__ __launch_bounds__(256) void accum_kernel(
    const int* __restrict__ baseLocal, const int* __restrict__ blockOffset,
    const int* __restrict__ sortedMeta, const uint4* __restrict__ sortedFeat,
    float* __restrict__ dense, int* __restrict__ worklist,
    int* __restrict__ nActive) {
  int p = blockIdx.x * blockDim.x + threadIdx.x;  // grid covers NSEG exactly
  int bo = blockOffset[p >> 10];
  int base = baseLocal[p] + bo;
  int nxt = ((p & 1023) != 1023) ? (baseLocal[p + 1] + bo)
                                 : blockOffset[(p >> 10) + 1];
  int c = nxt - base;
  float acc[CIN];
#pragma unroll
  for (int k = 0; k < CIN; k++) acc[k] = 0.0f;
  for (int j = 0; j < c; j++) {
    int e = sortedMeta[base + j];
    float pol = (float)((unsigned)e >> 31);
    acc[0] += pol;
    acc[1] += 1.0f - pol;
    uint4 w0 = sortedFeat[(size_t)(base + j) * 2];
    uint4 w1 = sortedFeat[(size_t)(base + j) * 2 + 1];
    acc[2] += bf2f((unsigned short)w0.x);  acc[3] += bf2f((unsigned short)(w0.x >> 16));
    acc[4] += bf2f((unsigned short)w0.y);  acc[5] += bf2f((unsigned short)(w0.y >> 16));
    acc[6] += bf2f((unsigned short)w0.z);  acc[7] += bf2f((unsigned short)(w0.z >> 16));
    acc[8] += bf2f((unsigned short)w0.w);  acc[9] += bf2f((unsigned short)(w0.w >> 16));
    acc[10] += bf2f((unsigned short)w1.x); acc[11] += bf2f((unsigned short)(w1.x >> 16));
    acc[12] += bf2f((unsigned short)w1.y); acc[13] += bf2f((unsigned short)(w1.y >> 16));
    acc[14] += bf2f((unsigned short)w1.z); acc[15] += bf2f((unsigned short)(w1.z >> 16));
    acc[16] += bf2f((unsigned short)w1.w); acc[17] += bf2f((unsigned short)(w1.w >> 16));
  }
  float inv = 1.0f / fmaxf((float)c, 1.0f);
#pragma unroll
  for (int k = 0; k < CIN; k++)
    dense[(size_t)k * NSEG + p] = acc[k] * inv;  // coalesced SoA store

  // wave-aggregated compaction: one atomic per wave, not per thread
  unsigned long long act = __ballot(c > 0);
  if (c > 0) {
    int lane = threadIdx.x & 63;
    int prefix = __popcll(act & ((1ull << lane) - 1ull));
    int leader = __ffsll((unsigned long long)act) - 1;
    int wbase = 0;
    if (lane == leader) wbase = atomicAdd(nActive, __popcll(act));
    wbase = __shfl(wbase, leader);
    worklist[wbase + prefix] = p;
  }
}

// ---- D: conv 3x3x18->32 at each active pixel, scatter to its events --------
__global__ __launch_bounds__(256) void conv_kernel(
    const float* __restrict__ dense, const float* __restrict__ weight,
    const float* __restrict__ bias, const int* __restrict__ baseLocal,
    const int* __restrict__ blockOffset, const int* __restrict__ sortedMeta,
    const int* __restrict__ worklist, const int* __restrict__ nActive,
    float* __restrict__ out) {
  int t = blockIdx.x * blockDim.x + threadIdx.x;
  if (t >= *nActive) return;
  int p = worklist[t];
  int xi = p % Ww;
  int rem = p / Ww;
  int yi = rem % Hh;
  int b = rem / Hh;
  float acc[OUT_CH];
#pragma unroll
  for (int o = 0; o < OUT_CH; o++) acc[o] = bias[o];  // uniform -> s_load
#pragma unroll 1
  for (int ky = 0; ky < 3; ky++) {
    int yy = yi + ky - 1;
    if (yy < 0 || yy >= Hh) continue;
#pragma unroll 1
    for (int kx = 0; kx < 3; kx++) {
      int xx = xi + kx - 1;
      if (xx < 0 || xx >= Ww) continue;
      int pix = (b * Hh + yy) * Ww + xx;
      const float* wp = weight + (ky * 3 + kx) * CIN * OUT_CH;
      float d[CIN];
#pragma unroll
      for (int ci = 0; ci < CIN; ci++)
        d[ci] = dense[(size_t)ci * NSEG + pix];  // saddr-form coalesced
#pragma unroll
      for (int ci = 0; ci < CIN; ci++) {
#pragma unroll
        for (int o = 0; o < OUT_CH; o++)
          acc[o] += d[ci] * wp[ci * OUT_CH + o];  // uniform idx -> s_load
      }
    }
  }
  int bo = blockOffset[p >> 10];
  int base = baseLocal[p] + bo;
  int nxt = ((p & 1023) != 1023) ? (baseLocal[p + 1] + bo)
                                 : blockOffset[(p >> 10) + 1];
  for (int j = 0; j < nxt - base; j++) {
    int ev = sortedMeta[base + j] & 0x7fffffff;
    float* op = out + (size_t)ev * OUT_CH;
#pragma unroll
    for (int o = 0; o < OUT_CH; o += 4)
      *(float4*)(op + o) = make_float4(acc[o], acc[o + 1], acc[o + 2], acc[o + 3]);
  }
}

extern "C" void kernel_launch(void* const* d_in, const int* in_sizes, int n_in,
                              void* d_out, int out_size, void* d_ws,
                              size_t ws_size, hipStream_t stream) {
  const float* events = (const float*)d_in[0];
  const float* features = (const float*)d_in[1];
  const float* weight = (const float*)d_in[2];
  const float* bias = (const float*)d_in[3];
  const int* offsets = (const int*)d_in[4];
  float* out = (float*)d_out;

  float* dense = (float*)d_ws;                        // NSEG*CIN f32 (SoA)
  uint4* sortedFeat = (uint4*)(dense + (size_t)NSEG * CIN);  // N_EV*32B
  int* sortedMeta = (int*)(sortedFeat + (size_t)N_EV * 2);   // N_EV
  int* keyArr = sortedMeta + N_EV;                    // N_EV
  int* rankArr = keyArr + N_EV;                       // N_EV
  int* hist = rankArr + N_EV;                         // NSEG
  int* baseLocal = hist + NSEG;                       // NSEG
  int* worklist = baseLocal + NSEG;                   // NSEG
  int* blockOffset = worklist + NSEG;                 // NBLK+1 (pad 1024)
  int* blockSum = blockOffset + 1024;                 // NBLK (pad 1024)
  int* nActive = blockSum + 1024;                     // 1

  hipMemsetAsync(hist, 0, (size_t)NSEG * sizeof(int), stream);
  hipMemsetAsync(nActive, 0, sizeof(int), stream);

  hist_rank_kernel<<<N_EV / 256, 256, 0, stream>>>(events, offsets, hist,
                                                   keyArr, rankArr);
  scan1_kernel<<<NBLK, 256, 0, stream>>>(hist, baseLocal, blockSum);
  scan2_kernel<<<1, 1024, 0, stream>>>(blockSum, blockOffset);
  scatter_feat_kernel<<<N_EV / 256, 256, 0, stream>>>(
      features, keyArr, rankArr, baseLocal, blockOffset, sortedFeat, sortedMeta);
  accum_kernel<<<NSEG / 256, 256, 0, stream>>>(baseLocal, blockOffset,
                                               sortedMeta, sortedFeat, dense,
                                               worklist, nActive);
  conv_kernel<<<NSEG / 256, 256, 0, stream>>>(dense, weight, bias, baseLocal,
                                              blockOffset, sortedMeta,
                                              worklist, nActive, out);
}

// Round 6
// 219.789 us; speedup vs baseline: 1.5665x; 1.5665x over previous
//
#include <hip/hip_runtime.h>

#define Hh 240
#define Ww 304
#define IN_CH 16
#define OUT_CH 32
#define Bb 8
#define N_PER 65536
#define N_EV (Bb * N_PER)      // 524288
#define CIN (IN_CH + 2)        // 18
#define NSEG (Bb * Hh * Ww)    // 583680 = 570 * 1024
#define NBLK 570               // scan blocks of 1024 elems

// fused conv tiling
#define TW 32
#define TH 8
#define HW_ 34                 // TW + 2 halo
#define HH_ 10                 // TH + 2 halo
#define PITCH 19               // 18 ch + 1 pad (odd -> 2-way LDS alias = free)
#define NXT_TILES 10           // ceil(304/32)
#define NYT_TILES 30           // 240/8

__device__ __forceinline__ unsigned short f2bf(float x) {
  unsigned u = __float_as_uint(x);
  unsigned r = u + 0x7fffu + ((u >> 16) & 1u);  // RNE
  return (unsigned short)(r >> 16);
}
__device__ __forceinline__ float bf2f(unsigned short b) {
  return __uint_as_float(((unsigned)b) << 16);
}

// ---- A: histogram + rank per event (one atomic pass) -----------------------
__global__ __launch_bounds__(256) void hist_rank_kernel(
    const float* __restrict__ events, const int* __restrict__ offsets,
    int* __restrict__ hist, int* __restrict__ keyArr, int* __restrict__ rankArr) {
  int i = blockIdx.x * blockDim.x + threadIdx.x;
  float4 ev = ((const float4*)events)[i];
  int yi = (int)rintf(ev.y * (float)Hh);
  yi = min(max(yi, 0), Hh - 1);
  int xi = (int)rintf(ev.x * (float)Ww);
  xi = min(max(xi, 0), Ww - 1);
  int b = 0;
#pragma unroll
  for (int j = 0; j < Bb; j++) b += (offsets[j] <= i) ? 1 : 0;
  int key = (b * Hh + yi) * Ww + xi;
  int pol = (ev.w != 0.0f) ? 1 : 0;
  keyArr[i] = key | (pol << 31);
  rankArr[i] = atomicAdd(&hist[key], 1);
}

// ---- S1: per-1024-block exclusive scan + block totals ----------------------
__global__ __launch_bounds__(256) void scan1_kernel(
    const int* __restrict__ hist, int* __restrict__ baseLocal,
    int* __restrict__ blockSum) {
  __shared__ int lds[256];
  int b = blockIdx.x, t = threadIdx.x;
  int idx = b * 1024 + t * 4;
  int4 v = *(const int4*)(hist + idx);
  int s0 = v.x, s1 = s0 + v.y, s2 = s1 + v.z, s3 = s2 + v.w;
  lds[t] = s3;
  __syncthreads();
  int val = s3;
  for (int off = 1; off < 256; off <<= 1) {
    int n = (t >= off) ? lds[t - off] : 0;
    __syncthreads();
    val += n;
    lds[t] = val;
    __syncthreads();
  }
  int excl = val - s3;
  int4 o;
  o.x = excl; o.y = excl + s0; o.z = excl + s1; o.w = excl + s2;
  *(int4*)(baseLocal + idx) = o;
  if (t == 255) blockSum[b] = val;
}

// ---- S2: scan of 570 block totals -----------------------------------------
__global__ __launch_bounds__(1024) void scan2_kernel(
    const int* __restrict__ blockSum, int* __restrict__ blockOffset) {
  __shared__ int lds[1024];
  int t = threadIdx.x;
  int v = (t < NBLK) ? blockSum[t] : 0;
  lds[t] = v;
  __syncthreads();
  int val = v;
  for (int off = 1; off < 1024; off <<= 1) {
    int n = (t >= off) ? lds[t - off] : 0;
    __syncthreads();
    val += n;
    lds[t] = val;
    __syncthreads();
  }
  if (t < NBLK) blockOffset[t] = val - v;
  if (t == 0) blockOffset[NBLK] = lds[1023];  // = N_EV
}

// ---- B: scatter features (bf16) + meta into sorted order -------------------
__global__ __launch_bounds__(256) void scatter_feat_kernel(
    const float* __restrict__ features, const int* __restrict__ keyArr,
    const int* __restrict__ rankArr, const int* __restrict__ baseLocal,
    const int* __restrict__ blockOffset, uint4* __restrict__ sortedFeat,
    int* __restrict__ sortedMeta) {
  int i = blockIdx.x * blockDim.x + threadIdx.x;
  int meta = keyArr[i];
  int key = meta & 0x7fffffff;
  int pos = baseLocal[key] + blockOffset[key >> 10] + rankArr[i];
  const float4* f = (const float4*)(features + (size_t)i * IN_CH);
  float4 f0 = f[0], f1 = f[1], f2 = f[2], f3 = f[3];
  uint4 w0, w1;
  w0.x = (unsigned)f2bf(f0.x) | ((unsigned)f2bf(f0.y) << 16);
  w0.y = (unsigned)f2bf(f0.z) | ((unsigned)f2bf(f0.w) << 16);
  w0.z = (unsigned)f2bf(f1.x) | ((unsigned)f2bf(f1.y) << 16);
  w0.w = (unsigned)f2bf(f1.z) | ((unsigned)f2bf(f1.w) << 16);
  w1.x = (unsigned)f2bf(f2.x) | ((unsigned)f2bf(f2.y) << 16);
  w1.y = (unsigned)f2bf(f2.z) | ((unsigned)f2bf(f2.w) << 16);
  w1.z = (unsigned)f2bf(f3.x) | ((unsigned)f2bf(f3.y) << 16);
  w1.w = (unsigned)f2bf(f3.z) | ((unsigned)f2bf(f3.w) << 16);
  sortedFeat[(size_t)pos * 2] = w0;
  sortedFeat[(size_t)pos * 2 + 1] = w1;
  sortedMeta[pos] = i | (meta & 0x80000000);
}

// ---- C: fused per-tile accum (LDS dense) + 3x3 conv + event scatter --------
// Block = one 32x8 output tile. LDS holds the 34x10x18 normalized halo.
__global__ __launch_bounds__(256) void fused_conv_kernel(
    const uint4* __restrict__ sortedFeat, const int* __restrict__ sortedMeta,
    const int* __restrict__ baseLocal, const int* __restrict__ blockOffset,
    const float* __restrict__ weight, const float* __restrict__ bias,
    float* __restrict__ out) {
  __shared__ float dsh[HH_ * HW_ * PITCH];  // 25.8 KB
  __shared__ int ibase[TH * TW];
  __shared__ int icnt[TH * TW];

  int blk = blockIdx.x;
  int xt = blk % NXT_TILES;
  int rem = blk / NXT_TILES;
  int yt = rem % NYT_TILES;
  int b = rem / NYT_TILES;
  int x0 = xt * TW, y0 = yt * TH;
  int tid = threadIdx.x;

  // ---- stage 1: build normalized dense halo in LDS ----
  for (int h = tid; h < HH_ * HW_; h += 256) {
    int hy = h / HW_, hx = h % HW_;
    int gy = y0 - 1 + hy, gx = x0 - 1 + hx;
    float acc[CIN];
#pragma unroll
    for (int k = 0; k < CIN; k++) acc[k] = 0.0f;
    int c = 0, base = 0;
    if (gy >= 0 && gy < Hh && gx >= 0 && gx < Ww) {
      int p = (b * Hh + gy) * Ww + gx;
      int bo = blockOffset[p >> 10];
      base = baseLocal[p] + bo;
      int nxt = ((p & 1023) != 1023) ? (baseLocal[p + 1] + bo)
                                     : blockOffset[(p >> 10) + 1];
      c = nxt - base;
      for (int j = 0; j < c; j++) {
        int e = sortedMeta[base + j];
        float pol = (float)((unsigned)e >> 31);
        acc[0] += pol;
        acc[1] += 1.0f - pol;
        uint4 w0 = sortedFeat[(size_t)(base + j) * 2];
        uint4 w1 = sortedFeat[(size_t)(base + j) * 2 + 1];
        acc[2] += bf2f((unsigned short)w0.x);  acc[3] += bf2f((unsigned short)(w0.x >> 16));
        acc[4] += bf2f((unsigned short)w0.y);  acc[5] += bf2f((unsigned short)(w0.y >> 16));
        acc[6] += bf2f((unsigned short)w0.z);  acc[7] += bf2f((unsigned short)(w0.z >> 16));
        acc[8] += bf2f((unsigned short)w0.w);  acc[9] += bf2f((unsigned short)(w0.w >> 16));
        acc[10] += bf2f((unsigned short)w1.x); acc[11] += bf2f((unsigned short)(w1.x >> 16));
        acc[12] += bf2f((unsigned short)w1.y); acc[13] += bf2f((unsigned short)(w1.y >> 16));
        acc[14] += bf2f((unsigned short)w1.z); acc[15] += bf2f((unsigned short)(w1.z >> 16));
        acc[16] += bf2f((unsigned short)w1.w); acc[17] += bf2f((unsigned short)(w1.w >> 16));
      }
    }
    float inv = 1.0f / fmaxf((float)c, 1.0f);
    float* dp = &dsh[h * PITCH];
#pragma unroll
    for (int k = 0; k < CIN; k++) dp[k] = acc[k] * inv;
    if (hx >= 1 && hx <= TW && hy >= 1 && hy <= TH) {
      int t = (hy - 1) * TW + (hx - 1);
      ibase[t] = base;
      icnt[t] = c;
    }
  }
  __syncthreads();

  // ---- stage 2: 3x3 conv from LDS, write this pixel's events ----
  int ox = tid & 31, oy = tid >> 5;
  int gx = x0 + ox;
  int c = icnt[tid];
  int base = ibase[tid];
  if (gx < Ww && c > 0) {
    float acc[OUT_CH];
#pragma unroll
    for (int o = 0; o < OUT_CH; o++) acc[o] = bias[o];  // uniform -> s_load
#pragma unroll 1
    for (int ky = 0; ky < 3; ky++) {
#pragma unroll 1
      for (int kx = 0; kx < 3; kx++) {
        const float* dp = &dsh[((oy + ky) * HW_ + (ox + kx)) * PITCH];
        float d[CIN];
#pragma unroll
        for (int ci = 0; ci < CIN; ci++) d[ci] = dp[ci];
        const float* wp = weight + (ky * 3 + kx) * CIN * OUT_CH;
#pragma unroll
        for (int ci = 0; ci < CIN; ci++) {
#pragma unroll
          for (int o = 0; o < OUT_CH; o++)
            acc[o] += d[ci] * wp[ci * OUT_CH + o];  // uniform idx -> s_load
        }
      }
    }
    for (int j = 0; j < c; j++) {
      int ev = sortedMeta[base + j] & 0x7fffffff;
      float* op = out + (size_t)ev * OUT_CH;
#pragma unroll
      for (int o = 0; o < OUT_CH; o += 4)
        *(float4*)(op + o) =
            make_float4(acc[o], acc[o + 1], acc[o + 2], acc[o + 3]);
    }
  }
}

extern "C" void kernel_launch(void* const* d_in, const int* in_sizes, int n_in,
                              void* d_out, int out_size, void* d_ws,
                              size_t ws_size, hipStream_t stream) {
  const float* events = (const float*)d_in[0];
  const float* features = (const float*)d_in[1];
  const float* weight = (const float*)d_in[2];
  const float* bias = (const float*)d_in[3];
  const int* offsets = (const int*)d_in[4];
  float* out = (float*)d_out;

  uint4* sortedFeat = (uint4*)d_ws;                   // N_EV * 32B
  int* sortedMeta = (int*)(sortedFeat + (size_t)N_EV * 2);  // N_EV
  int* keyArr = sortedMeta + N_EV;                    // N_EV
  int* rankArr = keyArr + N_EV;                       // N_EV
  int* hist = rankArr + N_EV;                         // NSEG
  int* baseLocal = hist + NSEG;                       // NSEG
  int* blockOffset = baseLocal + NSEG;                // NBLK+1 (pad 1024)
  int* blockSum = blockOffset + 1024;                 // NBLK (pad 1024)

  hipMemsetAsync(hist, 0, (size_t)NSEG * sizeof(int), stream);

  hist_rank_kernel<<<N_EV / 256, 256, 0, stream>>>(events, offsets, hist,
                                                   keyArr, rankArr);
  scan1_kernel<<<NBLK, 256, 0, stream>>>(hist, baseLocal, blockSum);
  scan2_kernel<<<1, 1024, 0, stream>>>(blockSum, blockOffset);
  scatter_feat_kernel<<<N_EV / 256, 256, 0, stream>>>(
      features, keyArr, rankArr, baseLocal, blockOffset, sortedFeat, sortedMeta);
  fused_conv_kernel<<<Bb * NYT_TILES * NXT_TILES, 256, 0, stream>>>(
      sortedFeat, sortedMeta, baseLocal, blockOffset, weight, bias, out);
}

// Round 7
// 208.135 us; speedup vs baseline: 1.6543x; 1.0560x over previous
//
#include <hip/hip_runtime.h>

#define Hh 240
#define Ww 304
#define IN_CH 16
#define OUT_CH 32
#define Bb 8
#define N_PER 65536
#define N_EV (Bb * N_PER)      // 524288
#define CIN (IN_CH + 2)        // 18
#define NSEG (Bb * Hh * Ww)    // 583680 = 570 * 1024
#define NBLK 570               // scan blocks of 1024 elems

// fused conv tiling
#define TW 32
#define TH 8
#define HW_ 34                 // TW + 2 halo
#define HH_ 10                 // TH + 2 halo
#define NXT_TILES 10           // ceil(304/32)
#define NYT_TILES 30           // 240/8
#define OPITCH 33              // out repack pitch (f32)

typedef __attribute__((ext_vector_type(8))) short bf16x8;
typedef __attribute__((ext_vector_type(4))) float f32x4;

__device__ __forceinline__ unsigned short f2bf(float x) {
  unsigned u = __float_as_uint(x);
  unsigned r = u + 0x7fffu + ((u >> 16) & 1u);  // RNE
  return (unsigned short)(r >> 16);
}
__device__ __forceinline__ float bf2f(unsigned short b) {
  return __uint_as_float(((unsigned)b) << 16);
}

// ---- A: histogram + rank per event (one atomic pass) -----------------------
__global__ __launch_bounds__(256) void hist_rank_kernel(
    const float* __restrict__ events, const int* __restrict__ offsets,
    int* __restrict__ hist, int* __restrict__ keyArr, int* __restrict__ rankArr) {
  int i = blockIdx.x * blockDim.x + threadIdx.x;
  float4 ev = ((const float4*)events)[i];
  int yi = (int)rintf(ev.y * (float)Hh);
  yi = min(max(yi, 0), Hh - 1);
  int xi = (int)rintf(ev.x * (float)Ww);
  xi = min(max(xi, 0), Ww - 1);
  int b = 0;
#pragma unroll
  for (int j = 0; j < Bb; j++) b += (offsets[j] <= i) ? 1 : 0;
  int key = (b * Hh + yi) * Ww + xi;
  int pol = (ev.w != 0.0f) ? 1 : 0;
  keyArr[i] = key | (pol << 31);
  rankArr[i] = atomicAdd(&hist[key], 1);
}

// ---- S1: per-1024-block exclusive scan + block totals ----------------------
__global__ __launch_bounds__(256) void scan1_kernel(
    const int* __restrict__ hist, int* __restrict__ baseLocal,
    int* __restrict__ blockSum) {
  __shared__ int lds[256];
  int b = blockIdx.x, t = threadIdx.x;
  int idx = b * 1024 + t * 4;
  int4 v = *(const int4*)(hist + idx);
  int s0 = v.x, s1 = s0 + v.y, s2 = s1 + v.z, s3 = s2 + v.w;
  lds[t] = s3;
  __syncthreads();
  int val = s3;
  for (int off = 1; off < 256; off <<= 1) {
    int n = (t >= off) ? lds[t - off] : 0;
    __syncthreads();
    val += n;
    lds[t] = val;
    __syncthreads();
  }
  int excl = val - s3;
  int4 o;
  o.x = excl; o.y = excl + s0; o.z = excl + s1; o.w = excl + s2;
  *(int4*)(baseLocal + idx) = o;
  if (t == 255) blockSum[b] = val;
}

// ---- S2: scan of 570 block totals -----------------------------------------
__global__ __launch_bounds__(1024) void scan2_kernel(
    const int* __restrict__ blockSum, int* __restrict__ blockOffset) {
  __shared__ int lds[1024];
  int t = threadIdx.x;
  int v = (t < NBLK) ? blockSum[t] : 0;
  lds[t] = v;
  __syncthreads();
  int val = v;
  for (int off = 1; off < 1024; off <<= 1) {
    int n = (t >= off) ? lds[t - off] : 0;
    __syncthreads();
    val += n;
    lds[t] = val;
    __syncthreads();
  }
  if (t < NBLK) blockOffset[t] = val - v;
  if (t == 0) blockOffset[NBLK] = lds[1023];  // = N_EV
}

// ---- B: scatter features (bf16) + meta into sorted order -------------------
__global__ __launch_bounds__(256) void scatter_feat_kernel(
    const float* __restrict__ features, const int* __restrict__ keyArr,
    const int* __restrict__ rankArr, const int* __restrict__ baseLocal,
    const int* __restrict__ blockOffset, uint4* __restrict__ sortedFeat,
    int* __restrict__ sortedMeta) {
  int i = blockIdx.x * blockDim.x + threadIdx.x;
  int meta = keyArr[i];
  int key = meta & 0x7fffffff;
  int pos = baseLocal[key] + blockOffset[key >> 10] + rankArr[i];
  const float4* f = (const float4*)(features + (size_t)i * IN_CH);
  float4 f0 = f[0], f1 = f[1], f2 = f[2], f3 = f[3];
  uint4 w0, w1;
  w0.x = (unsigned)f2bf(f0.x) | ((unsigned)f2bf(f0.y) << 16);
  w0.y = (unsigned)f2bf(f0.z) | ((unsigned)f2bf(f0.w) << 16);
  w0.z = (unsigned)f2bf(f1.x) | ((unsigned)f2bf(f1.y) << 16);
  w0.w = (unsigned)f2bf(f1.z) | ((unsigned)f2bf(f1.w) << 16);
  w1.x = (unsigned)f2bf(f2.x) | ((unsigned)f2bf(f2.y) << 16);
  w1.y = (unsigned)f2bf(f2.z) | ((unsigned)f2bf(f2.w) << 16);
  w1.z = (unsigned)f2bf(f3.x) | ((unsigned)f2bf(f3.y) << 16);
  w1.w = (unsigned)f2bf(f3.z) | ((unsigned)f2bf(f3.w) << 16);
  sortedFeat[(size_t)pos * 2] = w0;
  sortedFeat[(size_t)pos * 2 + 1] = w1;
  sortedMeta[pos] = i | (meta & 0x80000000);
}

// ---- C: fused per-tile accum (bf16 LDS halo) + MFMA conv + event scatter ---
// Block = one 32x8 tile. GEMM: M=256 pixels, K=162 (3ky x 54), N=32.
__global__ __launch_bounds__(256) void fused_conv_kernel(
    const uint4* __restrict__ sortedFeat, const int* __restrict__ sortedMeta,
    const int* __restrict__ baseLocal, const int* __restrict__ blockOffset,
    const float* __restrict__ weight, const float* __restrict__ bias,
    float* __restrict__ out) {
  // union: [halo bf16: HH_*HW_*18 shorts = 3060 uints (+12 pad)] then reused
  // as [out repack: 256*33 f32 = 8448 uints]
  __shared__ unsigned smem[256 * OPITCH];  // 33792 B
  __shared__ int ibase[TH * TW];
  __shared__ int icnt[TH * TW];

  int blk = blockIdx.x;
  int xt = blk % NXT_TILES;
  int rem = blk / NXT_TILES;
  int yt = rem % NYT_TILES;
  int b = rem / NYT_TILES;
  int x0 = xt * TW, y0 = yt * TH;
  int tid = threadIdx.x;

  if (tid < 12) smem[3060 + tid] = 0;  // zero A-read overrun pad (shorts 6120..6143)

  // ---- stage 1: build normalized bf16 dense halo in LDS ----
  for (int h = tid; h < HH_ * HW_; h += 256) {
    int hy = h / HW_, hx = h % HW_;
    int gy = y0 - 1 + hy, gx = x0 - 1 + hx;
    float acc[CIN];
#pragma unroll
    for (int k = 0; k < CIN; k++) acc[k] = 0.0f;
    int c = 0, base = 0;
    if (gy >= 0 && gy < Hh && gx >= 0 && gx < Ww) {
      int p = (b * Hh + gy) * Ww + gx;
      int bo = blockOffset[p >> 10];
      base = baseLocal[p] + bo;
      int nxt = ((p & 1023) != 1023) ? (baseLocal[p + 1] + bo)
                                     : blockOffset[(p >> 10) + 1];
      c = nxt - base;
      for (int j = 0; j < c; j++) {
        int e = sortedMeta[base + j];
        float pol = (float)((unsigned)e >> 31);
        acc[0] += pol;
        acc[1] += 1.0f - pol;
        uint4 w0 = sortedFeat[(size_t)(base + j) * 2];
        uint4 w1 = sortedFeat[(size_t)(base + j) * 2 + 1];
        acc[2] += bf2f((unsigned short)w0.x);  acc[3] += bf2f((unsigned short)(w0.x >> 16));
        acc[4] += bf2f((unsigned short)w0.y);  acc[5] += bf2f((unsigned short)(w0.y >> 16));
        acc[6] += bf2f((unsigned short)w0.z);  acc[7] += bf2f((unsigned short)(w0.z >> 16));
        acc[8] += bf2f((unsigned short)w0.w);  acc[9] += bf2f((unsigned short)(w0.w >> 16));
        acc[10] += bf2f((unsigned short)w1.x); acc[11] += bf2f((unsigned short)(w1.x >> 16));
        acc[12] += bf2f((unsigned short)w1.y); acc[13] += bf2f((unsigned short)(w1.y >> 16));
        acc[14] += bf2f((unsigned short)w1.z); acc[15] += bf2f((unsigned short)(w1.z >> 16));
        acc[16] += bf2f((unsigned short)w1.w); acc[17] += bf2f((unsigned short)(w1.w >> 16));
      }
    }
    float inv = 1.0f / fmaxf((float)c, 1.0f);
    unsigned* row = smem + 9 * h;  // 18 bf16 = 9 dwords, 4B-aligned
#pragma unroll
    for (int k = 0; k < 9; k++)
      row[k] = (unsigned)f2bf(acc[2 * k] * inv) |
               ((unsigned)f2bf(acc[2 * k + 1] * inv) << 16);
    if (hx >= 1 && hx <= TW && hy >= 1 && hy <= TH) {
      int t = (hy - 1) * TW + (hx - 1);
      ibase[t] = base;
      icnt[t] = c;
    }
  }
  __syncthreads();

  // ---- stage 2: MFMA GEMM from LDS halo ----
  int wv = tid >> 6, lane = tid & 63;
  int quad = lane >> 4, lrow = lane & 15;

  // B fragments: B[n = lane&15][k = quad*8+j], zero-padded for k_run >= 54
  bf16x8 bfr[3][2][2];  // [ky][khalf][ntile]
#pragma unroll
  for (int ky = 0; ky < 3; ky++) {
#pragma unroll
    for (int kh = 0; kh < 2; kh++) {
#pragma unroll
      for (int nt = 0; nt < 2; nt++) {
        int n = nt * 16 + lrow;
#pragma unroll
        for (int j = 0; j < 8; j++) {
          int kl = kh * 32 + quad * 8 + j;
          short w = 0;
          if (kl < 54) {
            int kx = kl / 18, ci = kl - kx * 18;
            w = (short)f2bf(weight[((ky * 3 + kx) * CIN + ci) * OUT_CH + n]);
          }
          bfr[ky][kh][nt][j] = w;
        }
      }
    }
  }

  f32x4 accf[4][2];
#pragma unroll
  for (int i = 0; i < 4; i++)
#pragma unroll
    for (int nt = 0; nt < 2; nt++) accf[i][nt] = (f32x4){0.f, 0.f, 0.f, 0.f};

  const unsigned* hp = smem;
#pragma unroll
  for (int i = 0; i < 4; i++) {  // m-tiles of this wave
    int t0 = (wv * 4 + i) * 16;
    int ox = (t0 & 31) + lrow;   // A: m = lane&15
    int oy = t0 >> 5;
#pragma unroll
    for (int ky = 0; ky < 3; ky++) {
      int idx0 = ((oy + ky) * HW_ + ox) * CIN;  // even
#pragma unroll
      for (int kh = 0; kh < 2; kh++) {
        union { bf16x8 v; unsigned u[4]; } a;
        int ui = (idx0 >> 1) + kh * 16 + quad * 4;
        a.u[0] = hp[ui]; a.u[1] = hp[ui + 1];
        a.u[2] = hp[ui + 2]; a.u[3] = hp[ui + 3];
        accf[i][0] = __builtin_amdgcn_mfma_f32_16x16x32_bf16(
            a.v, bfr[ky][kh][0], accf[i][0], 0, 0, 0);
        accf[i][1] = __builtin_amdgcn_mfma_f32_16x16x32_bf16(
            a.v, bfr[ky][kh][1], accf[i][1], 0, 0, 0);
      }
    }
  }
  __syncthreads();  // halo no longer needed; smem becomes out repack

  // ---- stage 3: repack D fragments (+bias) into LDS out buffer ----
  float* outsh = (float*)smem;
  float bn0 = bias[lrow], bn1 = bias[16 + lrow];  // D: col = lane&15
#pragma unroll
  for (int i = 0; i < 4; i++) {
    int tb = (wv * 4 + i) * 16 + quad * 4;  // D: row = quad*4 + r
#pragma unroll
    for (int r = 0; r < 4; r++) {
      outsh[(tb + r) * OPITCH + lrow] = accf[i][0][r] + bn0;
      outsh[(tb + r) * OPITCH + 16 + lrow] = accf[i][1][r] + bn1;
    }
  }
  __syncthreads();

  // ---- stage 4: write each pixel's events ----
  int gx = x0 + (tid & 31);
  int c = icnt[tid];
  int base = ibase[tid];
  if (gx < Ww && c > 0) {
    const float* row = outsh + tid * OPITCH;
    float4 o0 = make_float4(row[0], row[1], row[2], row[3]);
    float4 o1 = make_float4(row[4], row[5], row[6], row[7]);
    float4 o2 = make_float4(row[8], row[9], row[10], row[11]);
    float4 o3 = make_float4(row[12], row[13], row[14], row[15]);
    float4 o4 = make_float4(row[16], row[17], row[18], row[19]);
    float4 o5 = make_float4(row[20], row[21], row[22], row[23]);
    float4 o6 = make_float4(row[24], row[25], row[26], row[27]);
    float4 o7 = make_float4(row[28], row[29], row[30], row[31]);
    for (int j = 0; j < c; j++) {
      int ev = sortedMeta[base + j] & 0x7fffffff;
      float4* op = (float4*)(out + (size_t)ev * OUT_CH);
      op[0] = o0; op[1] = o1; op[2] = o2; op[3] = o3;
      op[4] = o4; op[5] = o5; op[6] = o6; op[7] = o7;
    }
  }
}

extern "C" void kernel_launch(void* const* d_in, const int* in_sizes, int n_in,
                              void* d_out, int out_size, void* d_ws,
                              size_t ws_size, hipStream_t stream) {
  const float* events = (const float*)d_in[0];
  const float* features = (const float*)d_in[1];
  const float* weight = (const float*)d_in[2];
  const float* bias = (const float*)d_in[3];
  const int* offsets = (const int*)d_in[4];
  float* out = (float*)d_out;

  uint4* sortedFeat = (uint4*)d_ws;                   // N_EV * 32B
  int* sortedMeta = (int*)(sortedFeat + (size_t)N_EV * 2);  // N_EV
  int* keyArr = sortedMeta + N_EV;                    // N_EV
  int* rankArr = keyArr + N_EV;                       // N_EV
  int* hist = rankArr + N_EV;                         // NSEG
  int* baseLocal = hist + NSEG;                       // NSEG
  int* blockOffset = baseLocal + NSEG;                // NBLK+1 (pad 1024)
  int* blockSum = blockOffset + 1024;                 // NBLK (pad 1024)

  hipMemsetAsync(hist, 0, (size_t)NSEG * sizeof(int), stream);

  hist_rank_kernel<<<N_EV / 256, 256, 0, stream>>>(events, offsets, hist,
                                                   keyArr, rankArr);
  scan1_kernel<<<NBLK, 256, 0, stream>>>(hist, baseLocal, blockSum);
  scan2_kernel<<<1, 1024, 0, stream>>>(blockSum, blockOffset);
  scatter_feat_kernel<<<N_EV / 256, 256, 0, stream>>>(
      features, keyArr, rankArr, baseLocal, blockOffset, sortedFeat, sortedMeta);
  fused_conv_kernel<<<Bb * NYT_TILES * NXT_TILES, 256, 0, stream>>>(
      sortedFeat, sortedMeta, baseLocal, blockOffset, weight, bias, out);
}

// Round 8
// 190.219 us; speedup vs baseline: 1.8101x; 1.0942x over previous
//
#include <hip/hip_runtime.h>

#define Hh 240
#define Ww 304
#define IN_CH 16
#define OUT_CH 32
#define Bb 8
#define N_PER 65536
#define N_EV (Bb * N_PER)      // 524288
#define CIN (IN_CH + 2)        // 18
#define NSEG (Bb * Hh * Ww)    // 583680 = 570 * 1024
#define NBLK 570               // scan blocks of 1024 elems

// fused conv tiling
#define TW 32
#define TH 8
#define HW_ 34                 // TW + 2 halo
#define HH_ 10                 // TH + 2 halo
#define NXT_TILES 10           // ceil(304/32)
#define NYT_TILES 30           // 240/8
#define OPITCH 33              // out repack pitch (f32)

typedef __attribute__((ext_vector_type(8))) short bf16x8;
typedef __attribute__((ext_vector_type(4))) float f32x4;

__device__ __forceinline__ unsigned short f2bf(float x) {
  unsigned u = __float_as_uint(x);
  unsigned r = u + 0x7fffu + ((u >> 16) & 1u);  // RNE
  return (unsigned short)(r >> 16);
}
__device__ __forceinline__ float bf2f(unsigned short b) {
  return __uint_as_float(((unsigned)b) << 16);
}

// ---- A: histogram + rank per event (one atomic pass) -----------------------
__global__ __launch_bounds__(256) void hist_rank_kernel(
    const float* __restrict__ events, const int* __restrict__ offsets,
    int* __restrict__ hist, int* __restrict__ keyArr, int* __restrict__ rankArr) {
  int i = blockIdx.x * blockDim.x + threadIdx.x;
  float4 ev = ((const float4*)events)[i];
  int yi = (int)rintf(ev.y * (float)Hh);
  yi = min(max(yi, 0), Hh - 1);
  int xi = (int)rintf(ev.x * (float)Ww);
  xi = min(max(xi, 0), Ww - 1);
  int b = 0;
#pragma unroll
  for (int j = 0; j < Bb; j++) b += (offsets[j] <= i) ? 1 : 0;
  int key = (b * Hh + yi) * Ww + xi;
  int pol = (ev.w != 0.0f) ? 1 : 0;
  keyArr[i] = key | (pol << 31);
  rankArr[i] = atomicAdd(&hist[key], 1);
}

// ---- S1: per-1024-block exclusive scan + block totals ----------------------
__global__ __launch_bounds__(256) void scan1_kernel(
    const int* __restrict__ hist, int* __restrict__ baseLocal,
    int* __restrict__ blockSum) {
  __shared__ int lds[256];
  int b = blockIdx.x, t = threadIdx.x;
  int idx = b * 1024 + t * 4;
  int4 v = *(const int4*)(hist + idx);
  int s0 = v.x, s1 = s0 + v.y, s2 = s1 + v.z, s3 = s2 + v.w;
  lds[t] = s3;
  __syncthreads();
  int val = s3;
  for (int off = 1; off < 256; off <<= 1) {
    int n = (t >= off) ? lds[t - off] : 0;
    __syncthreads();
    val += n;
    lds[t] = val;
    __syncthreads();
  }
  int excl = val - s3;
  int4 o;
  o.x = excl; o.y = excl + s0; o.z = excl + s1; o.w = excl + s2;
  *(int4*)(baseLocal + idx) = o;
  if (t == 255) blockSum[b] = val;
}

// ---- S2: scan of 570 block totals -----------------------------------------
__global__ __launch_bounds__(1024) void scan2_kernel(
    const int* __restrict__ blockSum, int* __restrict__ blockOffset) {
  __shared__ int lds[1024];
  int t = threadIdx.x;
  int v = (t < NBLK) ? blockSum[t] : 0;
  lds[t] = v;
  __syncthreads();
  int val = v;
  for (int off = 1; off < 1024; off <<= 1) {
    int n = (t >= off) ? lds[t - off] : 0;
    __syncthreads();
    val += n;
    lds[t] = val;
    __syncthreads();
  }
  if (t < NBLK) blockOffset[t] = val - v;
  if (t == 0) blockOffset[NBLK] = lds[1023];  // = N_EV
}

// ---- W: pre-pack weights to [ky][n][64] bf16, zero-padded k>=54 ------------
__global__ __launch_bounds__(256) void prep_weights_kernel(
    const float* __restrict__ weight, unsigned short* __restrict__ wprep) {
  int tid = threadIdx.x;
#pragma unroll
  for (int it = 0; it < 24; it++) {
    int idx = it * 256 + tid;             // < 3*32*64 = 6144
    int ky = idx >> 11;
    int rem = idx & 2047;
    int n = rem >> 6;
    int kl = rem & 63;
    unsigned short v = 0;
    if (kl < 54) {
      int kx = kl / 18, ci = kl - kx * 18;
      v = f2bf(weight[((ky * 3 + kx) * CIN + ci) * OUT_CH + n]);
    }
    wprep[idx] = v;
  }
}

// ---- B: scatter features (bf16) + meta into sorted order -------------------
__global__ __launch_bounds__(256) void scatter_feat_kernel(
    const float* __restrict__ features, const int* __restrict__ keyArr,
    const int* __restrict__ rankArr, const int* __restrict__ baseLocal,
    const int* __restrict__ blockOffset, uint4* __restrict__ sortedFeat,
    int* __restrict__ sortedMeta) {
  int i = blockIdx.x * blockDim.x + threadIdx.x;
  int meta = keyArr[i];
  int key = meta & 0x7fffffff;
  int pos = baseLocal[key] + blockOffset[key >> 10] + rankArr[i];
  const float4* f = (const float4*)(features + (size_t)i * IN_CH);
  float4 f0 = f[0], f1 = f[1], f2 = f[2], f3 = f[3];
  uint4 w0, w1;
  w0.x = (unsigned)f2bf(f0.x) | ((unsigned)f2bf(f0.y) << 16);
  w0.y = (unsigned)f2bf(f0.z) | ((unsigned)f2bf(f0.w) << 16);
  w0.z = (unsigned)f2bf(f1.x) | ((unsigned)f2bf(f1.y) << 16);
  w0.w = (unsigned)f2bf(f1.z) | ((unsigned)f2bf(f1.w) << 16);
  w1.x = (unsigned)f2bf(f2.x) | ((unsigned)f2bf(f2.y) << 16);
  w1.y = (unsigned)f2bf(f2.z) | ((unsigned)f2bf(f2.w) << 16);
  w1.z = (unsigned)f2bf(f3.x) | ((unsigned)f2bf(f3.y) << 16);
  w1.w = (unsigned)f2bf(f3.z) | ((unsigned)f2bf(f3.w) << 16);
  sortedFeat[(size_t)pos * 2] = w0;
  sortedFeat[(size_t)pos * 2 + 1] = w1;
  sortedMeta[pos] = i | (meta & 0x80000000);
}

// ---- C: fused per-tile accum (bf16 LDS halo) + MFMA conv + event scatter ---
// Block = one 32x8 tile. GEMM: M=256 pixels, K=162 (3ky x 54->64), N=32.
// smem union: [halo bf16: 3060 dwords (+12 zero pad)] then [repack 128x33 f32]
__global__ __launch_bounds__(256) void fused_conv_kernel(
    const uint4* __restrict__ sortedFeat, const int* __restrict__ sortedMeta,
    const int* __restrict__ baseLocal, const int* __restrict__ blockOffset,
    const unsigned short* __restrict__ wprep, const float* __restrict__ bias,
    float* __restrict__ out) {
  __shared__ unsigned smem[128 * OPITCH];  // 16896 B (>= 3072 dwords for halo)
  __shared__ int ibase[TH * TW];
  __shared__ int icnt[TH * TW];

  int blk = blockIdx.x;
  int xt = blk % NXT_TILES;
  int rem = blk / NXT_TILES;
  int yt = rem % NYT_TILES;
  int b = rem / NYT_TILES;
  int x0 = xt * TW, y0 = yt * TH;
  int tid = threadIdx.x;

  if (tid < 12) smem[3060 + tid] = 0;  // zero A-read overrun pad

  // ---- stage 1: build normalized bf16 dense halo in LDS ----
  for (int h = tid; h < HH_ * HW_; h += 256) {
    int hy = h / HW_, hx = h % HW_;
    int gy = y0 - 1 + hy, gx = x0 - 1 + hx;
    float acc[CIN];
#pragma unroll
    for (int k = 0; k < CIN; k++) acc[k] = 0.0f;
    int c = 0, base = 0;
    if (gy >= 0 && gy < Hh && gx >= 0 && gx < Ww) {
      int p = (b * Hh + gy) * Ww + gx;
      int bo = blockOffset[p >> 10];
      base = baseLocal[p] + bo;
      int nxt = ((p & 1023) != 1023) ? (baseLocal[p + 1] + bo)
                                     : blockOffset[(p >> 10) + 1];
      c = nxt - base;
      for (int j = 0; j < c; j++) {
        int e = sortedMeta[base + j];
        float pol = (float)((unsigned)e >> 31);
        acc[0] += pol;
        acc[1] += 1.0f - pol;
        uint4 w0 = sortedFeat[(size_t)(base + j) * 2];
        uint4 w1 = sortedFeat[(size_t)(base + j) * 2 + 1];
        acc[2] += bf2f((unsigned short)w0.x);  acc[3] += bf2f((unsigned short)(w0.x >> 16));
        acc[4] += bf2f((unsigned short)w0.y);  acc[5] += bf2f((unsigned short)(w0.y >> 16));
        acc[6] += bf2f((unsigned short)w0.z);  acc[7] += bf2f((unsigned short)(w0.z >> 16));
        acc[8] += bf2f((unsigned short)w0.w);  acc[9] += bf2f((unsigned short)(w0.w >> 16));
        acc[10] += bf2f((unsigned short)w1.x); acc[11] += bf2f((unsigned short)(w1.x >> 16));
        acc[12] += bf2f((unsigned short)w1.y); acc[13] += bf2f((unsigned short)(w1.y >> 16));
        acc[14] += bf2f((unsigned short)w1.z); acc[15] += bf2f((unsigned short)(w1.z >> 16));
        acc[16] += bf2f((unsigned short)w1.w); acc[17] += bf2f((unsigned short)(w1.w >> 16));
      }
    }
    float inv = 1.0f / fmaxf((float)c, 1.0f);
    unsigned* row = smem + 9 * h;  // 18 bf16 = 9 dwords
#pragma unroll
    for (int k = 0; k < 9; k++)
      row[k] = (unsigned)f2bf(acc[2 * k] * inv) |
               ((unsigned)f2bf(acc[2 * k + 1] * inv) << 16);
    if (hx >= 1 && hx <= TW && hy >= 1 && hy <= TH) {
      int t = (hy - 1) * TW + (hx - 1);
      ibase[t] = base;
      icnt[t] = c;
    }
  }
  __syncthreads();

  // ---- stage 2: MFMA GEMM from LDS halo (ky-outer to cut VGPR) ----
  int wv = tid >> 6, lane = tid & 63;
  int quad = lane >> 4, lrow = lane & 15;

  f32x4 accf[4][2];
#pragma unroll
  for (int i = 0; i < 4; i++)
#pragma unroll
    for (int nt = 0; nt < 2; nt++) accf[i][nt] = (f32x4){0.f, 0.f, 0.f, 0.f};

  const unsigned* hp = smem;
#pragma unroll
  for (int ky = 0; ky < 3; ky++) {
    // B fragments for this ky: one 16B load each (prepacked [ky][n][64])
    bf16x8 bfr[2][2];  // [khalf][ntile]
#pragma unroll
    for (int kh = 0; kh < 2; kh++)
#pragma unroll
      for (int nt = 0; nt < 2; nt++) {
        int n = nt * 16 + lrow;
        bfr[kh][nt] = *(const bf16x8*)(wprep + ((ky * 32 + n) << 6) +
                                       kh * 32 + quad * 8);
      }
#pragma unroll
    for (int i = 0; i < 4; i++) {  // m-tiles of this wave
      int t0 = (wv * 4 + i) * 16;
      int ox = (t0 & 31) + lrow;   // A: m = lane&15
      int oy = t0 >> 5;
      int idx0 = ((oy + ky) * HW_ + ox) * CIN;  // even (shorts)
#pragma unroll
      for (int kh = 0; kh < 2; kh++) {
        union { bf16x8 v; unsigned u[4]; } a;
        int ui = (idx0 >> 1) + kh * 16 + quad * 4;
        a.u[0] = hp[ui]; a.u[1] = hp[ui + 1];
        a.u[2] = hp[ui + 2]; a.u[3] = hp[ui + 3];
        accf[i][0] = __builtin_amdgcn_mfma_f32_16x16x32_bf16(
            a.v, bfr[kh][0], accf[i][0], 0, 0, 0);
        accf[i][1] = __builtin_amdgcn_mfma_f32_16x16x32_bf16(
            a.v, bfr[kh][1], accf[i][1], 0, 0, 0);
      }
    }
  }
  __syncthreads();  // halo dead; smem becomes out repack (128 rows x 33)

  // ---- stages 3+4, chunked (2 x 32 pixels per wave) to halve LDS ----
  float* outsh = (float*)smem;
  float bn0 = bias[lrow], bn1 = bias[16 + lrow];  // D: col = lane&15
  int gx = x0 + (tid & 31);
  int c = icnt[tid];
  int base = ibase[tid];
#pragma unroll
  for (int ch = 0; ch < 2; ch++) {
#pragma unroll
    for (int ii = 0; ii < 2; ii++) {
      int i = ch * 2 + ii;
      int lidx = ii * 16 + quad * 4;         // local row within chunk [0,32)
      int row = wv * 32 + lidx;
#pragma unroll
      for (int r = 0; r < 4; r++) {
        outsh[(row + r) * OPITCH + lrow] = accf[i][0][r] + bn0;
        outsh[(row + r) * OPITCH + 16 + lrow] = accf[i][1][r] + bn1;
      }
    }
    __syncthreads();
    if (((tid >> 5) & 1) == ch && gx < Ww && c > 0) {
      int row = (tid >> 6) * 32 + ((tid & 63) - ch * 32);
      const float* rp = outsh + row * OPITCH;
      float4 o0 = make_float4(rp[0], rp[1], rp[2], rp[3]);
      float4 o1 = make_float4(rp[4], rp[5], rp[6], rp[7]);
      float4 o2 = make_float4(rp[8], rp[9], rp[10], rp[11]);
      float4 o3 = make_float4(rp[12], rp[13], rp[14], rp[15]);
      float4 o4 = make_float4(rp[16], rp[17], rp[18], rp[19]);
      float4 o5 = make_float4(rp[20], rp[21], rp[22], rp[23]);
      float4 o6 = make_float4(rp[24], rp[25], rp[26], rp[27]);
      float4 o7 = make_float4(rp[28], rp[29], rp[30], rp[31]);
      for (int j = 0; j < c; j++) {
        int ev = sortedMeta[base + j] & 0x7fffffff;
        float4* op = (float4*)(out + (size_t)ev * OUT_CH);
        op[0] = o0; op[1] = o1; op[2] = o2; op[3] = o3;
        op[4] = o4; op[5] = o5; op[6] = o6; op[7] = o7;
      }
    }
    __syncthreads();
  }
}

extern "C" void kernel_launch(void* const* d_in, const int* in_sizes, int n_in,
                              void* d_out, int out_size, void* d_ws,
                              size_t ws_size, hipStream_t stream) {
  const float* events = (const float*)d_in[0];
  const float* features = (const float*)d_in[1];
  const float* weight = (const float*)d_in[2];
  const float* bias = (const float*)d_in[3];
  const int* offsets = (const int*)d_in[4];
  float* out = (float*)d_out;

  uint4* sortedFeat = (uint4*)d_ws;                   // N_EV * 32B
  int* sortedMeta = (int*)(sortedFeat + (size_t)N_EV * 2);  // N_EV
  int* keyArr = sortedMeta + N_EV;                    // N_EV
  int* rankArr = keyArr + N_EV;                       // N_EV
  int* hist = rankArr + N_EV;                         // NSEG
  int* baseLocal = hist + NSEG;                       // NSEG
  int* blockOffset = baseLocal + NSEG;                // NBLK+1 (pad 1024)
  int* blockSum = blockOffset + 1024;                 // NBLK (pad 1024)
  unsigned short* wprep = (unsigned short*)(blockSum + 1024);  // 6144 ushort

  hipMemsetAsync(hist, 0, (size_t)NSEG * sizeof(int), stream);

  hist_rank_kernel<<<N_EV / 256, 256, 0, stream>>>(events, offsets, hist,
                                                   keyArr, rankArr);
  prep_weights_kernel<<<1, 256, 0, stream>>>(weight, wprep);
  scan1_kernel<<<NBLK, 256, 0, stream>>>(hist, baseLocal, blockSum);
  scan2_kernel<<<1, 1024, 0, stream>>>(blockSum, blockOffset);
  scatter_feat_kernel<<<N_EV / 256, 256, 0, stream>>>(
      features, keyArr, rankArr, baseLocal, blockOffset, sortedFeat, sortedMeta);
  fused_conv_kernel<<<Bb * NYT_TILES * NXT_TILES, 256, 0, stream>>>(
      sortedFeat, sortedMeta, baseLocal, blockOffset, wprep, bias, out);
}